// Round 10
// baseline (488.951 us; speedup 1.0000x reference)
//
#include <hip/hip_runtime.h>
#include <math.h>

namespace {
constexpr int B_   = 8;
constexpr int DIM_ = 2048;
constexpr int H_   = 16;
constexpr int QLR_ = 1536;
constexpr int KVLR_= 512;
constexpr int DN_  = 128;
constexpr int DR_  = 64;
constexpr int DV_  = 128;
constexpr int TPRE_= 8191;
constexpr int CE_  = 576;    // KVLR + DR
constexpr int NCH_ = 64;     // chunks over T=8192
constexpr int CT_  = 128;    // t per chunk
constexpr int TS_  = 16;     // rows per LDS subtile (double-buffered)
constexpr int NS_  = CT_ / TS_;  // 8 subtiles
constexpr int PSTR_= 20;     // p_lds row stride
constexpr int NPRE_= 384;    // pre-kernel grid
constexpr int NPOST_=256;    // post-kernel grid
constexpr float EPS_ = 1e-6f;
constexpr float SCALE_ = 0.07216878364870322f; // (DN+DR)^-0.5

// workspace layout (float offsets)
constexpr size_t WS_QLAT  = 0;
constexpr size_t WS_KVPE  = WS_QLAT  + (size_t)B_*QLR_;
constexpr size_t WS_PENEW = WS_KVPE  + (size_t)B_*CE_;
constexpr size_t WS_BAR   = WS_PENEW + (size_t)B_*DR_;   // 2 barrier counters
constexpr size_t WS_QNOPE = WS_BAR   + 16;
constexpr size_t WS_QT    = WS_QNOPE + (size_t)B_*H_*DN_;   // qTT: [b][h][576]
constexpr size_t WS_MLOC  = WS_QT    + (size_t)B_*CE_*H_;
constexpr size_t WS_LLOC  = WS_MLOC  + (size_t)B_*H_*NCH_;
constexpr size_t WS_OUT2  = WS_LLOC  + (size_t)B_*H_*NCH_;
constexpr size_t WS_OPART = WS_OUT2  + (size_t)B_*DIM_;     // [b][h][chunk][512]
} // namespace

__device__ __forceinline__ void gload16(const float* src, float* ldsDst) {
  __builtin_amdgcn_global_load_lds((const __attribute__((address_space(1))) void*)src,
                                   (__attribute__((address_space(3))) void*)ldsDst,
                                   16, 0, 0);
}

// sum across each 16-lane group via DPP (VALU pipe, keeps DS unit free)
__device__ __forceinline__ float rsum16(float v) {
  int x = __float_as_int(v);
  v += __int_as_float(__builtin_amdgcn_update_dpp(0, x, 0xB1, 0xF, 0xF, true));  // quad_perm xor1
  x = __float_as_int(v);
  v += __int_as_float(__builtin_amdgcn_update_dpp(0, x, 0x4E, 0xF, 0xF, true));  // quad_perm xor2
  x = __float_as_int(v);
  v += __int_as_float(__builtin_amdgcn_update_dpp(0, x, 0x141, 0xF, 0xF, true)); // row_half_mirror
  x = __float_as_int(v);
  v += __int_as_float(__builtin_amdgcn_update_dpp(0, x, 0x140, 0xF, 0xF, true)); // row_mirror
  return v;
}

// workgroup barrier that drains ONLY lgkmcnt (LDS) — leaves global_load_lds
// prefetch (vmcnt) in flight across the barrier.
__device__ __forceinline__ void barrier_lgkm() {
  asm volatile("s_waitcnt lgkmcnt(0)" ::: "memory");
  __builtin_amdgcn_s_barrier();
  __builtin_amdgcn_sched_barrier(0);
}

// software grid barrier (validated correct in an earlier round): monotonic
// counter, device-scope release/acquire. All blocks must be co-resident
// (register-light phases only; grids well under capacity).
__device__ __forceinline__ void gridbar(unsigned* bar, unsigned target) {
  __syncthreads();
  if (threadIdx.x == 0) {
    __threadfence();
    atomicAdd(bar, 1u);
    int guard = 0;
    while (__hip_atomic_load(bar, __ATOMIC_ACQUIRE, __HIP_MEMORY_SCOPE_AGENT) < target) {
      __builtin_amdgcn_s_sleep(2);
      if (++guard > (1 << 28)) break;
    }
  }
  __syncthreads();
}

// ---------------- PRE: k1 (q/kv GEMV + rope) -> k3 (q up-proj) -> k4 (wkv_b absorb) ----------------
// 384 blocks x 256 thr, 7 KB LDS, register-light -> trivially co-resident.
__global__ __launch_bounds__(256) void mla_pre(
    const float* __restrict__ x, const float* __restrict__ fcos, const float* __restrict__ fsin,
    const float* __restrict__ wqa, const float* __restrict__ bqa,
    const float* __restrict__ qnw, const float* __restrict__ wqb, const float* __restrict__ bqb,
    const float* __restrict__ wkva, const float* __restrict__ bkva,
    const float* __restrict__ wkvb, float* __restrict__ ws) {
  __shared__ float red[7 * 32 * B_];   // phase C reduction (7 KB)
  __shared__ float qs_s[B_];
  unsigned* bar = (unsigned*)(ws + WS_BAR);
  const int bid = blockIdx.x;
  const int tid = threadIdx.x;
  const int w = tid >> 6, l = tid & 63;

  // ---- phase A (= k1): 2 rows/wave GEMV, fused pe-rope; blocks 0..263 ----
  if (bid < 264) {
    const int r0 = (bid * 4 + w) * 2;
    const float* W; const float* bias; int rr;
    if (r0 < QLR_) { W = wqa;  bias = bqa;  rr = r0; }
    else           { W = wkva; bias = bkva; rr = r0 - QLR_; }
    const float4* w0p = (const float4*)(W + (size_t)rr * DIM_);
    const float4* w1p = (const float4*)(W + (size_t)(rr + 1) * DIM_);
    const float4* x4  = (const float4*)x;
    float4 wv0[8], wv1[8];
#pragma unroll
    for (int j = 0; j < 8; ++j) { wv0[j] = w0p[l + 64 * j]; wv1[j] = w1p[l + 64 * j]; }
    float acc0[B_], acc1[B_];
#pragma unroll
    for (int b = 0; b < B_; ++b) { acc0[b] = 0.f; acc1[b] = 0.f; }
#pragma unroll
    for (int b = 0; b < B_; ++b) {
#pragma unroll
      for (int j = 0; j < 8; ++j) {
        const float4 xv = x4[b * (DIM_ / 4) + l + 64 * j];
        acc0[b] = fmaf(wv0[j].x, xv.x, fmaf(wv0[j].y, xv.y, fmaf(wv0[j].z, xv.z, fmaf(wv0[j].w, xv.w, acc0[b]))));
        acc1[b] = fmaf(wv1[j].x, xv.x, fmaf(wv1[j].y, xv.y, fmaf(wv1[j].z, xv.z, fmaf(wv1[j].w, xv.w, acc1[b]))));
      }
    }
#pragma unroll
    for (int b = 0; b < B_; ++b)
#pragma unroll
      for (int s = 32; s; s >>= 1) {
        acc0[b] += __shfl_xor(acc0[b], s);
        acc1[b] += __shfl_xor(acc1[b], s);
      }
    if (l == 0) {
      const float b0 = bias[rr], b1 = bias[rr + 1];
      if (r0 < QLR_) {
        float* outp = ws + WS_QLAT;
#pragma unroll
        for (int b = 0; b < B_; ++b) {
          outp[b * QLR_ + r0]     = acc0[b] + b0;
          outp[b * QLR_ + r0 + 1] = acc1[b] + b1;
        }
      } else if (rr < KVLR_) {
        float* outp = ws + WS_KVPE;  // raw kv latent; rms in k5
#pragma unroll
        for (int b = 0; b < B_; ++b) {
          outp[b * CE_ + rr]     = acc0[b] + b0;
          outp[b * CE_ + rr + 1] = acc1[b] + b1;
        }
      } else {
        const int i = (rr - KVLR_) >> 1;
        const float c = fcos[i], s = fsin[i];
        float* pen = ws + WS_PENEW;
#pragma unroll
        for (int b = 0; b < B_; ++b) {
          const float xr = acc0[b] + b0, xi = acc1[b] + b1;
          pen[b * DR_ + 2 * i]     = xr * c - xi * s;
          pen[b * DR_ + 2 * i + 1] = xr * s + xi * c;
        }
      }
    }
  }
  gridbar(bar, NPRE_);

  // ---- phase B (= k3): per-block q-rms scale + up-projection; all 384 blocks ----
  {
    { // block-local q ssq from L2
      const int bq = tid >> 5, l32 = tid & 31;
      const float4* ql4 = (const float4*)(ws + WS_QLAT + (size_t)bq * QLR_);
      float ss = 0.f;
#pragma unroll
      for (int j = 0; j < 12; ++j) {
        const float4 v = ql4[l32 + 32 * j];
        ss = fmaf(v.x, v.x, fmaf(v.y, v.y, fmaf(v.z, v.z, fmaf(v.w, v.w, ss))));
      }
#pragma unroll
      for (int d = 16; d; d >>= 1) ss += __shfl_xor(ss, d, 32);
      if (l32 == 0) qs_s[bq] = 1.0f / sqrtf(ss / (float)QLR_ + EPS_);
      __syncthreads();
    }
    const int r0 = bid * 8 + w * 2;  // 0..3070
    const float4* w0p = (const float4*)(wqb + (size_t)r0 * QLR_);
    const float4* w1p = (const float4*)(wqb + (size_t)(r0 + 1) * QLR_);
    const float4* g4  = (const float4*)qnw;
    const float4* x4  = (const float4*)(ws + WS_QLAT);
    float4 wg0[6], wg1[6];
#pragma unroll
    for (int j = 0; j < 6; ++j) {
      const int c4 = l + 64 * j;
      const float4 a = w0p[c4], bb = w1p[c4], g = g4[c4];
      wg0[j].x = a.x * g.x; wg0[j].y = a.y * g.y; wg0[j].z = a.z * g.z; wg0[j].w = a.w * g.w;
      wg1[j].x = bb.x * g.x; wg1[j].y = bb.y * g.y; wg1[j].z = bb.z * g.z; wg1[j].w = bb.w * g.w;
    }
    float acc0[B_], acc1[B_];
#pragma unroll
    for (int b = 0; b < B_; ++b) { acc0[b] = 0.f; acc1[b] = 0.f; }
#pragma unroll
    for (int b = 0; b < B_; ++b) {
#pragma unroll
      for (int j = 0; j < 6; ++j) {
        const float4 xv = x4[b * (QLR_ / 4) + l + 64 * j];
        acc0[b] = fmaf(wg0[j].x, xv.x, fmaf(wg0[j].y, xv.y, fmaf(wg0[j].z, xv.z, fmaf(wg0[j].w, xv.w, acc0[b]))));
        acc1[b] = fmaf(wg1[j].x, xv.x, fmaf(wg1[j].y, xv.y, fmaf(wg1[j].z, xv.z, fmaf(wg1[j].w, xv.w, acc1[b]))));
      }
    }
#pragma unroll
    for (int b = 0; b < B_; ++b)
#pragma unroll
      for (int s = 32; s; s >>= 1) {
        acc0[b] += __shfl_xor(acc0[b], s);
        acc1[b] += __shfl_xor(acc1[b], s);
      }
    if (l == 0) {
      const int h = r0 / (DN_ + DR_);
      const int j0 = r0 - h * (DN_ + DR_);
      const float b0 = bqb[r0], b1 = bqb[r0 + 1];
      if (j0 < DN_) {
        float* qn = ws + WS_QNOPE;
#pragma unroll
        for (int b = 0; b < B_; ++b) {
          const float sb = qs_s[b];
          qn[(b * H_ + h) * DN_ + j0]     = acc0[b] * sb + b0;
          qn[(b * H_ + h) * DN_ + j0 + 1] = acc1[b] * sb + b1;
        }
      } else {
        const int i = (j0 - DN_) >> 1;
        const float c = fcos[i], s = fsin[i];
        float* qTT = ws + WS_QT;
#pragma unroll
        for (int b = 0; b < B_; ++b) {
          const float sb = qs_s[b];
          const float xr = acc0[b] * sb + b0, xi = acc1[b] * sb + b1;
          qTT[((size_t)(b * H_ + h)) * CE_ + KVLR_ + 2 * i]     = xr * c - xi * s;
          qTT[((size_t)(b * H_ + h)) * CE_ + KVLR_ + 2 * i + 1] = xr * s + xi * c;
        }
      }
    }
  }
  gridbar(bar, 2 * NPRE_);

  // ---- phase C (= k4): q_abs = q_nope @ wkv_b[:, :128]; blocks 0..255 ----
  if (bid < 256) {
    const int h = bid >> 4, strip = bid & 15;
    const int c = tid & 31, dg = tid >> 5;
    const int cg = strip * 32 + c;
    const float* qn = ws + WS_QNOPE;
    float acc[B_];
#pragma unroll
    for (int b = 0; b < B_; ++b) acc[b] = 0.f;
    const float* wp = wkvb + (size_t)h * 256 * KVLR_ + cg;
#pragma unroll
    for (int dd = 0; dd < 16; ++dd) {
      const int d = dg * 16 + dd;
      const float wv = wp[(size_t)d * KVLR_];
#pragma unroll
      for (int b = 0; b < B_; ++b) acc[b] = fmaf(qn[(b * H_ + h) * DN_ + d], wv, acc[b]);
    }
    if (dg > 0) {
#pragma unroll
      for (int b = 0; b < B_; ++b) red[(((dg - 1) * 32) + c) * B_ + b] = acc[b];
    }
    __syncthreads();
    if (dg == 0) {
      float* qTT = ws + WS_QT;
#pragma unroll
      for (int b = 0; b < B_; ++b) {
        float v = acc[b];
#pragma unroll
        for (int g = 0; g < 7; ++g) v += red[(g * 32 + c) * B_ + b];
        qTT[((size_t)(b * H_ + h)) * CE_ + cg] = v;
      }
    }
  }
}

// ---------------- K5: flash-decode, 4-heads-per-thread score (halved score DS traffic) ----------------
// grid (64, 8) x 512 thr. Score: thread = (cs16, hg4 [4 heads], wave [2 rows]);
// q[4][36] persistent in VGPRs (~144 regs; no launch_bounds cap -> no spill).
// Each kv element read by 4 h-groups instead of 8 -> score LDS traffic halves;
// FMA:b128 = 16:1. PV / softmax / staging unchanged.
__global__ __launch_bounds__(512) void mla_k5(const float* __restrict__ kvpre,
                                              const float* __restrict__ pepre,
                                              const float* __restrict__ kvnw,
                                              float* __restrict__ ws) {
  __shared__ float kv_lds[2][TS_ * CE_];  // 73.7 KB
  __shared__ float p_lds[TS_ * PSTR_];
  __shared__ float m_st[H_], l_st[H_], f_st[H_];
  __shared__ float redw[8];
  __shared__ float kvs_s;

  const int b = blockIdx.y, chunk = blockIdx.x;
  const int t0 = chunk * CT_;
  const int tid = threadIdx.x;
  const int w = tid >> 6, l = tid & 63;
  // score roles: 16 cs x 4 hg x 8 waves (2 rows each)
  const int cs = l & 15;             // c-split: 36 floats each
  const int hg = (l >> 4) & 3;       // 4 heads each: 4*hg .. 4*hg+3
  // PV roles
  const int c4p = tid >> 2, h4p = tid & 3;

  const float* kvraw = ws + WS_KVPE + b * CE_;
  const float* penew = ws + WS_PENEW + b * DR_;

  auto stageKV = [&](float* buf, int s) {
    const int ts0 = t0 + s * TS_;
#pragma unroll
    for (int k = 0; k < 5; ++k) {
      const int i = tid + 512 * k;
      if (i < (TS_ * CE_) / 4) {
        const int tl = i / 144;
        const int c4 = i - tl * 144;
        const int tgl = ts0 + tl;
        const float* src;
        if (tgl < TPRE_) {
          src = (c4 < 128) ? (kvpre + ((size_t)b * TPRE_ + tgl) * KVLR_ + 4 * c4)
                           : (pepre + ((size_t)b * TPRE_ + tgl) * DR_ + 4 * (c4 - 128));
        } else {
          src = (c4 < 128) ? (kvraw + 4 * c4) : (penew + 4 * (c4 - 128));
        }
        gload16(src, buf + (size_t)i * 4);
      }
    }
  };

  stageKV(kv_lds[0], 0);   // start HBM early

  { // per-block kv rms scale for this b
    const float v = ws[WS_KVPE + b * CE_ + tid];
    float ss = v * v;
#pragma unroll
    for (int d = 32; d; d >>= 1) ss += __shfl_xor(ss, d);
    if (l == 0) redw[w] = ss;
    __syncthreads();
    if (tid == 0) {
      float s = 0.f;
#pragma unroll
      for (int g = 0; g < 8; ++g) s += redw[g];
      kvs_s = 1.0f / sqrtf(s / (float)KVLR_ + EPS_);
    }
  }

  // --- persistent q registers: heads 4*hg..4*hg+3, c-range [cs*36, cs*36+36) ---
  float4 qv0[9], qv1[9], qv2[9], qv3[9];
  {
    const float* qb = ws + WS_QT + ((size_t)(b * H_) + 4 * hg) * CE_ + cs * 36;
#pragma unroll
    for (int j = 0; j < 9; ++j) {
      qv0[j] = *(const float4*)(qb + 0 * CE_ + 4 * j);
      qv1[j] = *(const float4*)(qb + 1 * CE_ + 4 * j);
      qv2[j] = *(const float4*)(qb + 2 * CE_ + 4 * j);
      qv3[j] = *(const float4*)(qb + 3 * CE_ + 4 * j);
    }
  }
  if (tid < H_) { m_st[tid] = -3.4e38f; l_st[tid] = 0.f; }

  float o[4][4];
#pragma unroll
  for (int cc = 0; cc < 4; ++cc)
#pragma unroll
    for (int hh = 0; hh < 4; ++hh) o[cc][hh] = 0.f;

  for (int s = 0; s < NS_; ++s) {         // 8 subtiles of 16 rows
    __syncthreads();                       // full: drains stage(s) vmcnt + prior LDS
    if (s + 1 < NS_) stageKV(kv_lds[(s + 1) & 1], s + 1);
    float* bufc = kv_lds[s & 1];

    if (chunk == NCH_ - 1 && s == NS_ - 1) {  // new-token kv rms fixup (row 15)
      float* row = bufc + (TS_ - 1) * CE_;
      row[tid] = row[tid] * kvnw[tid] * kvs_s;
      __syncthreads();
    }

    // --- scores: 2 rows x 4 heads x 36 c per thread; q from regs ---
    {
      const float* kr0 = bufc + (w * 2) * CE_ + cs * 36;
      const float* kr1 = kr0 + CE_;
      float a00 = 0.f, a01 = 0.f, a02 = 0.f, a03 = 0.f;
      float a10 = 0.f, a11 = 0.f, a12 = 0.f, a13 = 0.f;
#pragma unroll
      for (int j = 0; j < 9; ++j) {
        const float4 k0 = *(const float4*)(kr0 + 4 * j);
        const float4 k1 = *(const float4*)(kr1 + 4 * j);
        const float4 q0 = qv0[j], q1 = qv1[j], q2 = qv2[j], q3 = qv3[j];
        a00 = fmaf(k0.x, q0.x, fmaf(k0.y, q0.y, fmaf(k0.z, q0.z, fmaf(k0.w, q0.w, a00))));
        a01 = fmaf(k0.x, q1.x, fmaf(k0.y, q1.y, fmaf(k0.z, q1.z, fmaf(k0.w, q1.w, a01))));
        a02 = fmaf(k0.x, q2.x, fmaf(k0.y, q2.y, fmaf(k0.z, q2.z, fmaf(k0.w, q2.w, a02))));
        a03 = fmaf(k0.x, q3.x, fmaf(k0.y, q3.y, fmaf(k0.z, q3.z, fmaf(k0.w, q3.w, a03))));
        a10 = fmaf(k1.x, q0.x, fmaf(k1.y, q0.y, fmaf(k1.z, q0.z, fmaf(k1.w, q0.w, a10))));
        a11 = fmaf(k1.x, q1.x, fmaf(k1.y, q1.y, fmaf(k1.z, q1.z, fmaf(k1.w, q1.w, a11))));
        a12 = fmaf(k1.x, q2.x, fmaf(k1.y, q2.y, fmaf(k1.z, q2.z, fmaf(k1.w, q2.w, a12))));
        a13 = fmaf(k1.x, q3.x, fmaf(k1.y, q3.y, fmaf(k1.z, q3.z, fmaf(k1.w, q3.w, a13))));
      }
      a00 = rsum16(a00); a01 = rsum16(a01); a02 = rsum16(a02); a03 = rsum16(a03);
      a10 = rsum16(a10); a11 = rsum16(a11); a12 = rsum16(a12); a13 = rsum16(a13);
      if (cs == 0) {
        float4 v0, v1;
        v0.x = a00 * SCALE_; v0.y = a01 * SCALE_; v0.z = a02 * SCALE_; v0.w = a03 * SCALE_;
        v1.x = a10 * SCALE_; v1.y = a11 * SCALE_; v1.z = a12 * SCALE_; v1.w = a13 * SCALE_;
        *(float4*)(p_lds + (w * 2) * PSTR_ + 4 * hg)     = v0;
        *(float4*)(p_lds + (w * 2 + 1) * PSTR_ + 4 * hg) = v1;
      }
    }
    barrier_lgkm();   // p_lds ready; prefetch vmcnt NOT drained

    // --- online softmax: threads 0..255 = 16 h x 16 t ---
    if (tid < 256) {
      const int h2 = tid >> 4, tl2 = tid & 15;
      const float sv = p_lds[tl2 * PSTR_ + h2];
      float msub = sv;
#pragma unroll
      for (int d = 8; d; d >>= 1) msub = fmaxf(msub, __shfl_xor(msub, d, 16));
      const float mold = m_st[h2];
      const float mnew = fmaxf(mold, msub);
      const float e = __expf(sv - mnew);
      float lsum = e;
#pragma unroll
      for (int d = 8; d; d >>= 1) lsum += __shfl_xor(lsum, d, 16);
      p_lds[tl2 * PSTR_ + h2] = e;
      if (tl2 == 0) {
        const float fac = __expf(mold - mnew);
        f_st[h2] = fac;
        l_st[h2] = l_st[h2] * fac + lsum;
        m_st[h2] = mnew;
      }
    }
    barrier_lgkm();   // p/f/m/l ready; prefetch still in flight

    // --- PV accumulate: o[c-quad][h-quad] over 16 t ---
    {
      const float4 fv = *(const float4*)(f_st + 4 * h4p);
#pragma unroll
      for (int cc = 0; cc < 4; ++cc) {
        o[cc][0] *= fv.x; o[cc][1] *= fv.y; o[cc][2] *= fv.z; o[cc][3] *= fv.w;
      }
#pragma unroll 8
      for (int t = 0; t < TS_; ++t) {
        const float4 kq = *(const float4*)(bufc + t * CE_ + 4 * c4p);
        const float4 pq = *(const float4*)(p_lds + t * PSTR_ + 4 * h4p);
        o[0][0] = fmaf(pq.x, kq.x, o[0][0]); o[0][1] = fmaf(pq.y, kq.x, o[0][1]);
        o[0][2] = fmaf(pq.z, kq.x, o[0][2]); o[0][3] = fmaf(pq.w, kq.x, o[0][3]);
        o[1][0] = fmaf(pq.x, kq.y, o[1][0]); o[1][1] = fmaf(pq.y, kq.y, o[1][1]);
        o[1][2] = fmaf(pq.z, kq.y, o[1][2]); o[1][3] = fmaf(pq.w, kq.y, o[1][3]);
        o[2][0] = fmaf(pq.x, kq.z, o[2][0]); o[2][1] = fmaf(pq.y, kq.z, o[2][1]);
        o[2][2] = fmaf(pq.z, kq.z, o[2][2]); o[2][3] = fmaf(pq.w, kq.z, o[2][3]);
        o[3][0] = fmaf(pq.x, kq.w, o[3][0]); o[3][1] = fmaf(pq.y, kq.w, o[3][1]);
        o[3][2] = fmaf(pq.z, kq.w, o[3][2]); o[3][3] = fmaf(pq.w, kq.w, o[3][3]);
      }
    }
  }

  // --- write chunk partials ---
  {
    float* Op = ws + WS_OPART;
#pragma unroll
    for (int hh = 0; hh < 4; ++hh) {
      const int h = 4 * h4p + hh;
      float4 v;
      v.x = o[0][hh]; v.y = o[1][hh]; v.z = o[2][hh]; v.w = o[3][hh];
      *(float4*)(Op + ((size_t)(b * H_ + h) * NCH_ + chunk) * KVLR_ + 4 * c4p) = v;
    }
    if (tid < H_) {
      ws[WS_MLOC + (b * H_ + tid) * NCH_ + chunk] = m_st[tid];
      ws[WS_LLOC + (b * H_ + tid) * NCH_ + chunk] = l_st[tid];
    }
  }
}

// ---------------- POST: k6 (combine + project) -> k7 (output GEMV) ----------------
// 256 blocks x 256 thr, 2.3 KB LDS -> trivially co-resident.
__global__ __launch_bounds__(256) void mla_post(const float* __restrict__ wkvb,
                                                const float* __restrict__ wo,
                                                const float* __restrict__ wob,
                                                float* __restrict__ ws,
                                                float* __restrict__ out) {
  __shared__ float wgt[NCH_];
  __shared__ float ao[KVLR_];
  __shared__ float Linv;
  unsigned* bar = (unsigned*)(ws + WS_BAR) + 1;
  const int bid = blockIdx.x;
  const int tid = threadIdx.x;
  const int w = tid >> 6, l = tid & 63;

  // ---- phase A (= k6): blocks 0..127 = (h, b) ----
  if (bid < H_ * B_) {
    const int h = bid & 15, b = bid >> 4;
    if (tid < NCH_) {   // one wave: combine weights over 64 chunks
      const float m = ws[WS_MLOC + (b * H_ + h) * NCH_ + tid];
      float M = m;
#pragma unroll
      for (int s = 32; s; s >>= 1) M = fmaxf(M, __shfl_xor(M, s));
      const float wv = __expf(m - M);
      wgt[tid] = wv;
      float lv = ws[WS_LLOC + (b * H_ + h) * NCH_ + tid] * wv;
#pragma unroll
      for (int s = 32; s; s >>= 1) lv += __shfl_xor(lv, s);
      if (tid == 0) Linv = 1.0f / lv;
    }
    __syncthreads();
    const float* Ob = ws + WS_OPART + (size_t)(b * H_ + h) * NCH_ * KVLR_;
    float s0 = 0.f, s1 = 0.f;
#pragma unroll 4
    for (int i = 0; i < NCH_; ++i) {
      const float wv = wgt[i];
      s0 = fmaf(wv, Ob[(size_t)i * KVLR_ + tid], s0);
      s1 = fmaf(wv, Ob[(size_t)i * KVLR_ + tid + 256], s1);
    }
    const float li = Linv;
    ao[tid] = s0 * li;
    ao[tid + 256] = s1 * li;
    __syncthreads();

    const float4 ax = *(const float4*)(ao + 4 * l);
    const float4 bx = *(const float4*)(ao + 256 + 4 * l);
    float* out2 = ws + WS_OUT2 + b * DIM_ + h * DV_;
#pragma unroll 2
    for (int k = 0; k < 32; k += 2) {
      const int v0 = w * 32 + k;
      const float4* w20 = (const float4*)(wkvb + ((size_t)h * 256 + DN_ + v0) * KVLR_);
      const float4* w21 = (const float4*)(wkvb + ((size_t)h * 256 + DN_ + v0 + 1) * KVLR_);
      const float4 a0 = w20[l], c0 = w20[64 + l];
      const float4 a1 = w21[l], c1 = w21[64 + l];
      float t0 = fmaf(a0.x, ax.x, fmaf(a0.y, ax.y, fmaf(a0.z, ax.z, fmaf(a0.w, ax.w,
                 fmaf(c0.x, bx.x, fmaf(c0.y, bx.y, fmaf(c0.z, bx.z, c0.w * bx.w)))))));
      float t1 = fmaf(a1.x, ax.x, fmaf(a1.y, ax.y, fmaf(a1.z, ax.z, fmaf(a1.w, ax.w,
                 fmaf(c1.x, bx.x, fmaf(c1.y, bx.y, fmaf(c1.z, bx.z, c1.w * bx.w)))))));
#pragma unroll
      for (int d = 32; d; d >>= 1) {
        t0 += __shfl_xor(t0, d);
        t1 += __shfl_xor(t1, d);
      }
      if (l == 0) { out2[v0] = t0; out2[v0 + 1] = t1; }
    }
  }
  gridbar(bar, NPOST_);

  // ---- phase B (= k7): y = out2 @ wo^T + wo_b, 2 rows/wave; all 256 blocks ----
  {
    const int r0 = (bid * 4 + w) * 2;  // 0..2046
    const float4* w0p = (const float4*)(wo + (size_t)r0 * DIM_);
    const float4* w1p = (const float4*)(wo + (size_t)(r0 + 1) * DIM_);
    const float4* x4  = (const float4*)(ws + WS_OUT2);
    float4 wv0[8], wv1[8];
#pragma unroll
    for (int j = 0; j < 8; ++j) { wv0[j] = w0p[l + 64 * j]; wv1[j] = w1p[l + 64 * j]; }
    float acc0[B_], acc1[B_];
#pragma unroll
    for (int b = 0; b < B_; ++b) { acc0[b] = 0.f; acc1[b] = 0.f; }
#pragma unroll
    for (int b = 0; b < B_; ++b) {
#pragma unroll
      for (int j = 0; j < 8; ++j) {
        const float4 xv = x4[b * (DIM_ / 4) + l + 64 * j];
        acc0[b] = fmaf(wv0[j].x, xv.x, fmaf(wv0[j].y, xv.y, fmaf(wv0[j].z, xv.z, fmaf(wv0[j].w, xv.w, acc0[b]))));
        acc1[b] = fmaf(wv1[j].x, xv.x, fmaf(wv1[j].y, xv.y, fmaf(wv1[j].z, xv.z, fmaf(wv1[j].w, xv.w, acc1[b]))));
      }
    }
#pragma unroll
    for (int b = 0; b < B_; ++b)
#pragma unroll
      for (int s = 32; s; s >>= 1) {
        acc0[b] += __shfl_xor(acc0[b], s);
        acc1[b] += __shfl_xor(acc1[b], s);
      }
    if (l == 0) {
      const float b0 = wob[r0], b1 = wob[r0 + 1];
#pragma unroll
      for (int b = 0; b < B_; ++b) {
        out[b * DIM_ + r0]     = acc0[b] + b0;
        out[b * DIM_ + r0 + 1] = acc1[b] + b1;
      }
    }
  }
}

extern "C" void kernel_launch(void* const* d_in, const int* in_sizes, int n_in,
                              void* d_out, int out_size, void* d_ws, size_t ws_size,
                              hipStream_t stream) {
  (void)in_sizes; (void)n_in; (void)out_size; (void)ws_size;
  const float* x     = (const float*)d_in[0];
  const float* fcos  = (const float*)d_in[2];
  const float* fsin  = (const float*)d_in[3];
  const float* kvpre = (const float*)d_in[4];
  const float* pepre = (const float*)d_in[5];
  const float* wqa   = (const float*)d_in[6];
  const float* bqa   = (const float*)d_in[7];
  const float* qnw   = (const float*)d_in[8];
  const float* wqb   = (const float*)d_in[9];
  const float* bqb   = (const float*)d_in[10];
  const float* wkva  = (const float*)d_in[11];
  const float* bkva  = (const float*)d_in[12];
  const float* kvnw  = (const float*)d_in[13];
  const float* wkvb  = (const float*)d_in[14];
  const float* wo    = (const float*)d_in[15];
  const float* wob   = (const float*)d_in[16];
  float* ws  = (float*)d_ws;
  float* out = (float*)d_out;

  hipMemsetAsync((char*)d_ws + WS_BAR * sizeof(float), 0, 16, stream);
  mla_pre<<<dim3(NPRE_), dim3(256), 0, stream>>>(x, fcos, fsin, wqa, bqa, qnw, wqb, bqb,
                                                 wkva, bkva, wkvb, ws);
  mla_k5<<<dim3(NCH_, B_), dim3(512), 0, stream>>>(kvpre, pepre, kvnw, ws);
  mla_post<<<dim3(NPOST_), dim3(256), 0, stream>>>(wkvb, wo, wob, ws, out);
}

// Round 11
// 365.256 us; speedup vs baseline: 1.3387x; 1.3387x over previous
//
#include <hip/hip_runtime.h>
#include <math.h>

namespace {
constexpr int B_   = 8;
constexpr int DIM_ = 2048;
constexpr int H_   = 16;
constexpr int QLR_ = 1536;
constexpr int KVLR_= 512;
constexpr int DN_  = 128;
constexpr int DR_  = 64;
constexpr int DV_  = 128;
constexpr int TPRE_= 8191;
constexpr int CE_  = 576;    // KVLR + DR
constexpr int NCH_ = 64;     // chunks over T=8192
constexpr int CT_  = 128;    // t per chunk
constexpr int TS_  = 16;     // rows per LDS subtile (double-buffered)
constexpr int NS_  = CT_ / TS_;  // 8 subtiles
constexpr int PSTR_= 20;     // p_lds row stride
constexpr float EPS_ = 1e-6f;
constexpr float SCALE_ = 0.07216878364870322f; // (DN+DR)^-0.5

// workspace layout (float offsets)
constexpr size_t WS_QLAT  = 0;
constexpr size_t WS_KVPE  = WS_QLAT  + (size_t)B_*QLR_;
constexpr size_t WS_PENEW = WS_KVPE  + (size_t)B_*CE_;
constexpr size_t WS_QNOPE = WS_PENEW + (size_t)B_*DR_;
constexpr size_t WS_QT    = WS_QNOPE + (size_t)B_*H_*DN_;   // qTT: [b][h][576]
constexpr size_t WS_MLOC  = WS_QT    + (size_t)B_*CE_*H_;
constexpr size_t WS_LLOC  = WS_MLOC  + (size_t)B_*H_*NCH_;
constexpr size_t WS_OUT2  = WS_LLOC  + (size_t)B_*H_*NCH_;
constexpr size_t WS_OPART = WS_OUT2  + (size_t)B_*DIM_;     // [b][h][chunk][512]
} // namespace

__device__ __forceinline__ void gload16(const float* src, float* ldsDst) {
  __builtin_amdgcn_global_load_lds((const __attribute__((address_space(1))) void*)src,
                                   (__attribute__((address_space(3))) void*)ldsDst,
                                   16, 0, 0);
}

// sum across each 16-lane group via DPP (VALU pipe, keeps DS unit free)
__device__ __forceinline__ float rsum16(float v) {
  int x = __float_as_int(v);
  v += __int_as_float(__builtin_amdgcn_update_dpp(0, x, 0xB1, 0xF, 0xF, true));  // quad_perm xor1
  x = __float_as_int(v);
  v += __int_as_float(__builtin_amdgcn_update_dpp(0, x, 0x4E, 0xF, 0xF, true));  // quad_perm xor2
  x = __float_as_int(v);
  v += __int_as_float(__builtin_amdgcn_update_dpp(0, x, 0x141, 0xF, 0xF, true)); // row_half_mirror
  x = __float_as_int(v);
  v += __int_as_float(__builtin_amdgcn_update_dpp(0, x, 0x140, 0xF, 0xF, true)); // row_mirror
  return v;
}

// workgroup barrier that drains ONLY lgkmcnt (LDS) — leaves global_load_lds
// prefetch (vmcnt) in flight across the barrier.
__device__ __forceinline__ void barrier_lgkm() {
  asm volatile("s_waitcnt lgkmcnt(0)" ::: "memory");
  __builtin_amdgcn_s_barrier();
  __builtin_amdgcn_sched_barrier(0);
}

// ---------------- K1: q_latent & kvpe GEMV, 2 rows/wave, fused pe-rope ----------------
__global__ __launch_bounds__(256) void mla_k1(const float* __restrict__ x,
                                              const float* __restrict__ wqa,
                                              const float* __restrict__ bqa,
                                              const float* __restrict__ wkva,
                                              const float* __restrict__ bkva,
                                              const float* __restrict__ fcos,
                                              const float* __restrict__ fsin,
                                              float* __restrict__ ws) {
  const int w = threadIdx.x >> 6, l = threadIdx.x & 63;
  const int r0 = (blockIdx.x * 4 + w) * 2;  // 0..2110 even
  const float* W; const float* bias; int rr;
  if (r0 < QLR_) { W = wqa;  bias = bqa;  rr = r0; }
  else           { W = wkva; bias = bkva; rr = r0 - QLR_; }
  const float4* w0p = (const float4*)(W + (size_t)rr * DIM_);
  const float4* w1p = (const float4*)(W + (size_t)(rr + 1) * DIM_);
  const float4* x4  = (const float4*)x;
  float4 wv0[8], wv1[8];
#pragma unroll
  for (int j = 0; j < 8; ++j) { wv0[j] = w0p[l + 64 * j]; wv1[j] = w1p[l + 64 * j]; }
  float acc0[B_], acc1[B_];
#pragma unroll
  for (int b = 0; b < B_; ++b) { acc0[b] = 0.f; acc1[b] = 0.f; }
#pragma unroll
  for (int b = 0; b < B_; ++b) {
#pragma unroll
    for (int j = 0; j < 8; ++j) {
      const float4 xv = x4[b * (DIM_ / 4) + l + 64 * j];
      acc0[b] = fmaf(wv0[j].x, xv.x, fmaf(wv0[j].y, xv.y, fmaf(wv0[j].z, xv.z, fmaf(wv0[j].w, xv.w, acc0[b]))));
      acc1[b] = fmaf(wv1[j].x, xv.x, fmaf(wv1[j].y, xv.y, fmaf(wv1[j].z, xv.z, fmaf(wv1[j].w, xv.w, acc1[b]))));
    }
  }
#pragma unroll
  for (int b = 0; b < B_; ++b)
#pragma unroll
    for (int s = 32; s; s >>= 1) {
      acc0[b] += __shfl_xor(acc0[b], s);
      acc1[b] += __shfl_xor(acc1[b], s);
    }
  if (l == 0) {
    const float b0 = bias[rr], b1 = bias[rr + 1];
    if (r0 < QLR_) {
      float* out = ws + WS_QLAT;   // raw; rms applied in k3
#pragma unroll
      for (int b = 0; b < B_; ++b) {
        out[b * QLR_ + r0]     = acc0[b] + b0;
        out[b * QLR_ + r0 + 1] = acc1[b] + b1;
      }
    } else if (rr < KVLR_) {
      float* out = ws + WS_KVPE;   // raw kv latent; rms applied in k5
#pragma unroll
      for (int b = 0; b < B_; ++b) {
        out[b * CE_ + rr]     = acc0[b] + b0;
        out[b * CE_ + rr + 1] = acc1[b] + b1;
      }
    } else {
      const int i = (rr - KVLR_) >> 1;
      const float c = fcos[i], s = fsin[i];
      float* pen = ws + WS_PENEW;
#pragma unroll
      for (int b = 0; b < B_; ++b) {
        const float xr = acc0[b] + b0, xi = acc1[b] + b1;
        pen[b * DR_ + 2 * i]     = xr * c - xi * s;
        pen[b * DR_ + 2 * i + 1] = xr * s + xi * c;
      }
    }
  }
}

// ---------------- K3: per-block q-rms scale + q = rms(q_lat)*g @ wq_b^T + b ----------------
__global__ __launch_bounds__(256) void mla_k3(const float* __restrict__ qnw,
                                              const float* __restrict__ wqb,
                                              const float* __restrict__ bqb,
                                              const float* __restrict__ fcos,
                                              const float* __restrict__ fsin,
                                              float* __restrict__ ws) {
  __shared__ float qs_s[B_];
  const int tid = threadIdx.x;
  { // block-local q ssq (48 KB from L2)
    const int bq = tid >> 5, l32 = tid & 31;
    const float4* ql4 = (const float4*)(ws + WS_QLAT + (size_t)bq * QLR_);
    float ss = 0.f;
#pragma unroll
    for (int j = 0; j < 12; ++j) {
      const float4 v = ql4[l32 + 32 * j];
      ss = fmaf(v.x, v.x, fmaf(v.y, v.y, fmaf(v.z, v.z, fmaf(v.w, v.w, ss))));
    }
#pragma unroll
    for (int d = 16; d; d >>= 1) ss += __shfl_xor(ss, d, 32);
    if (l32 == 0) qs_s[bq] = 1.0f / sqrtf(ss / (float)QLR_ + EPS_);
    __syncthreads();
  }
  const int w = tid >> 6, l = tid & 63;
  const int r0 = blockIdx.x * 8 + w * 2;  // 0..3070
  const float4* w0p = (const float4*)(wqb + (size_t)r0 * QLR_);
  const float4* w1p = (const float4*)(wqb + (size_t)(r0 + 1) * QLR_);
  const float4* g4  = (const float4*)qnw;
  const float4* x4  = (const float4*)(ws + WS_QLAT);
  float4 wg0[6], wg1[6];
#pragma unroll
  for (int j = 0; j < 6; ++j) {
    const int c4 = l + 64 * j;
    const float4 a = w0p[c4], bb = w1p[c4], g = g4[c4];
    wg0[j].x = a.x * g.x; wg0[j].y = a.y * g.y; wg0[j].z = a.z * g.z; wg0[j].w = a.w * g.w;
    wg1[j].x = bb.x * g.x; wg1[j].y = bb.y * g.y; wg1[j].z = bb.z * g.z; wg1[j].w = bb.w * g.w;
  }
  float acc0[B_], acc1[B_];
#pragma unroll
  for (int b = 0; b < B_; ++b) { acc0[b] = 0.f; acc1[b] = 0.f; }
#pragma unroll
  for (int b = 0; b < B_; ++b) {
#pragma unroll
    for (int j = 0; j < 6; ++j) {
      const float4 xv = x4[b * (QLR_ / 4) + l + 64 * j];
      acc0[b] = fmaf(wg0[j].x, xv.x, fmaf(wg0[j].y, xv.y, fmaf(wg0[j].z, xv.z, fmaf(wg0[j].w, xv.w, acc0[b]))));
      acc1[b] = fmaf(wg1[j].x, xv.x, fmaf(wg1[j].y, xv.y, fmaf(wg1[j].z, xv.z, fmaf(wg1[j].w, xv.w, acc1[b]))));
    }
  }
#pragma unroll
  for (int b = 0; b < B_; ++b)
#pragma unroll
    for (int s = 32; s; s >>= 1) {
      acc0[b] += __shfl_xor(acc0[b], s);
      acc1[b] += __shfl_xor(acc1[b], s);
    }
  if (l == 0) {
    const int h = r0 / (DN_ + DR_);
    const int j0 = r0 - h * (DN_ + DR_);
    const float b0 = bqb[r0], b1 = bqb[r0 + 1];
    if (j0 < DN_) {
      float* qn = ws + WS_QNOPE;
#pragma unroll
      for (int b = 0; b < B_; ++b) {
        const float sb = qs_s[b];
        qn[(b * H_ + h) * DN_ + j0]     = acc0[b] * sb + b0;
        qn[(b * H_ + h) * DN_ + j0 + 1] = acc1[b] * sb + b1;
      }
    } else {
      const int i = (j0 - DN_) >> 1;
      const float c = fcos[i], s = fsin[i];
      float* qTT = ws + WS_QT;
#pragma unroll
      for (int b = 0; b < B_; ++b) {
        const float sb = qs_s[b];
        const float xr = acc0[b] * sb + b0, xi = acc1[b] * sb + b1;
        qTT[((size_t)(b * H_ + h)) * CE_ + KVLR_ + 2 * i]     = xr * c - xi * s;
        qTT[((size_t)(b * H_ + h)) * CE_ + KVLR_ + 2 * i + 1] = xr * s + xi * c;
      }
    }
  }
}

// ---------------- K4: q_abs[b][h][c] = sum_d q_nope[b][h][d] * wkv_b[h][d][c] ----------------
__global__ __launch_bounds__(256) void mla_k4(const float* __restrict__ wkvb,
                                              float* __restrict__ ws) {
  __shared__ float red[7 * 32 * B_];
  const int h = blockIdx.y;
  const int strip = blockIdx.x;
  const int tid = threadIdx.x;
  const int c = tid & 31, dg = tid >> 5;
  const int cg = strip * 32 + c;
  const float* qn = ws + WS_QNOPE;
  float acc[B_];
#pragma unroll
  for (int b = 0; b < B_; ++b) acc[b] = 0.f;
  const float* wp = wkvb + (size_t)h * 256 * KVLR_ + cg;
#pragma unroll
  for (int dd = 0; dd < 16; ++dd) {
    const int d = dg * 16 + dd;
    const float wv = wp[(size_t)d * KVLR_];
#pragma unroll
    for (int b = 0; b < B_; ++b) acc[b] = fmaf(qn[(b * H_ + h) * DN_ + d], wv, acc[b]);
  }
  if (dg > 0) {
#pragma unroll
    for (int b = 0; b < B_; ++b) red[(((dg - 1) * 32) + c) * B_ + b] = acc[b];
  }
  __syncthreads();
  if (dg == 0) {
    float* qTT = ws + WS_QT;
#pragma unroll
    for (int b = 0; b < B_; ++b) {
      float v = acc[b];
#pragma unroll
      for (int g = 0; g < 7; ++g) v += red[(g * 32 + c) * B_ + b];
      qTT[((size_t)(b * H_ + h)) * CE_ + cg] = v;
    }
  }
}

// ---------------- K5: flash-decode, 4-heads-per-thread score ----------------
// grid (64, 8) x 512 thr, 73.7 KB LDS -> 2 blocks/CU. Score: thread = (cs16,
// hg4 [4 heads], wave [2 rows]); q[4][36] persistent in VGPRs. Each kv element
// read by 4 h-groups instead of 8 -> score LDS traffic halved; FMA:b128 = 16:1.
__global__ __launch_bounds__(512) void mla_k5(const float* __restrict__ kvpre,
                                              const float* __restrict__ pepre,
                                              const float* __restrict__ kvnw,
                                              float* __restrict__ ws) {
  __shared__ float kv_lds[2][TS_ * CE_];  // 73.7 KB
  __shared__ float p_lds[TS_ * PSTR_];
  __shared__ float m_st[H_], l_st[H_], f_st[H_];
  __shared__ float redw[8];
  __shared__ float kvs_s;

  const int b = blockIdx.y, chunk = blockIdx.x;
  const int t0 = chunk * CT_;
  const int tid = threadIdx.x;
  const int w = tid >> 6, l = tid & 63;
  const int cs = l & 15;             // c-split: 36 floats each
  const int hg = (l >> 4) & 3;       // 4 heads each: 4*hg .. 4*hg+3
  const int c4p = tid >> 2, h4p = tid & 3;

  const float* kvraw = ws + WS_KVPE + b * CE_;
  const float* penew = ws + WS_PENEW + b * DR_;

  auto stageKV = [&](float* buf, int s) {
    const int ts0 = t0 + s * TS_;
#pragma unroll
    for (int k = 0; k < 5; ++k) {
      const int i = tid + 512 * k;
      if (i < (TS_ * CE_) / 4) {
        const int tl = i / 144;
        const int c4 = i - tl * 144;
        const int tgl = ts0 + tl;
        const float* src;
        if (tgl < TPRE_) {
          src = (c4 < 128) ? (kvpre + ((size_t)b * TPRE_ + tgl) * KVLR_ + 4 * c4)
                           : (pepre + ((size_t)b * TPRE_ + tgl) * DR_ + 4 * (c4 - 128));
        } else {
          src = (c4 < 128) ? (kvraw + 4 * c4) : (penew + 4 * (c4 - 128));
        }
        gload16(src, buf + (size_t)i * 4);
      }
    }
  };

  stageKV(kv_lds[0], 0);   // start HBM early

  { // per-block kv rms scale for this b
    const float v = ws[WS_KVPE + b * CE_ + tid];
    float ss = v * v;
#pragma unroll
    for (int d = 32; d; d >>= 1) ss += __shfl_xor(ss, d);
    if (l == 0) redw[w] = ss;
    __syncthreads();
    if (tid == 0) {
      float s = 0.f;
#pragma unroll
      for (int g = 0; g < 8; ++g) s += redw[g];
      kvs_s = 1.0f / sqrtf(s / (float)KVLR_ + EPS_);
    }
  }

  // --- persistent q registers: heads 4*hg..4*hg+3, c-range [cs*36, cs*36+36) ---
  float4 qv0[9], qv1[9], qv2[9], qv3[9];
  {
    const float* qb = ws + WS_QT + ((size_t)(b * H_) + 4 * hg) * CE_ + cs * 36;
#pragma unroll
    for (int j = 0; j < 9; ++j) {
      qv0[j] = *(const float4*)(qb + 0 * CE_ + 4 * j);
      qv1[j] = *(const float4*)(qb + 1 * CE_ + 4 * j);
      qv2[j] = *(const float4*)(qb + 2 * CE_ + 4 * j);
      qv3[j] = *(const float4*)(qb + 3 * CE_ + 4 * j);
    }
  }
  if (tid < H_) { m_st[tid] = -3.4e38f; l_st[tid] = 0.f; }

  float o[4][4];
#pragma unroll
  for (int cc = 0; cc < 4; ++cc)
#pragma unroll
    for (int hh = 0; hh < 4; ++hh) o[cc][hh] = 0.f;

  for (int s = 0; s < NS_; ++s) {         // 8 subtiles of 16 rows
    __syncthreads();                       // full: drains stage(s) vmcnt + prior LDS
    if (s + 1 < NS_) stageKV(kv_lds[(s + 1) & 1], s + 1);
    float* bufc = kv_lds[s & 1];

    if (chunk == NCH_ - 1 && s == NS_ - 1) {  // new-token kv rms fixup (row 15)
      float* row = bufc + (TS_ - 1) * CE_;
      row[tid] = row[tid] * kvnw[tid] * kvs_s;
      __syncthreads();
    }

    // --- scores: 2 rows x 4 heads x 36 c per thread; q from regs ---
    {
      const float* kr0 = bufc + (w * 2) * CE_ + cs * 36;
      const float* kr1 = kr0 + CE_;
      float a00 = 0.f, a01 = 0.f, a02 = 0.f, a03 = 0.f;
      float a10 = 0.f, a11 = 0.f, a12 = 0.f, a13 = 0.f;
#pragma unroll
      for (int j = 0; j < 9; ++j) {
        const float4 k0 = *(const float4*)(kr0 + 4 * j);
        const float4 k1 = *(const float4*)(kr1 + 4 * j);
        const float4 q0 = qv0[j], q1 = qv1[j], q2 = qv2[j], q3 = qv3[j];
        a00 = fmaf(k0.x, q0.x, fmaf(k0.y, q0.y, fmaf(k0.z, q0.z, fmaf(k0.w, q0.w, a00))));
        a01 = fmaf(k0.x, q1.x, fmaf(k0.y, q1.y, fmaf(k0.z, q1.z, fmaf(k0.w, q1.w, a01))));
        a02 = fmaf(k0.x, q2.x, fmaf(k0.y, q2.y, fmaf(k0.z, q2.z, fmaf(k0.w, q2.w, a02))));
        a03 = fmaf(k0.x, q3.x, fmaf(k0.y, q3.y, fmaf(k0.z, q3.z, fmaf(k0.w, q3.w, a03))));
        a10 = fmaf(k1.x, q0.x, fmaf(k1.y, q0.y, fmaf(k1.z, q0.z, fmaf(k1.w, q0.w, a10))));
        a11 = fmaf(k1.x, q1.x, fmaf(k1.y, q1.y, fmaf(k1.z, q1.z, fmaf(k1.w, q1.w, a11))));
        a12 = fmaf(k1.x, q2.x, fmaf(k1.y, q2.y, fmaf(k1.z, q2.z, fmaf(k1.w, q2.w, a12))));
        a13 = fmaf(k1.x, q3.x, fmaf(k1.y, q3.y, fmaf(k1.z, q3.z, fmaf(k1.w, q3.w, a13))));
      }
      a00 = rsum16(a00); a01 = rsum16(a01); a02 = rsum16(a02); a03 = rsum16(a03);
      a10 = rsum16(a10); a11 = rsum16(a11); a12 = rsum16(a12); a13 = rsum16(a13);
      if (cs == 0) {
        float4 v0, v1;
        v0.x = a00 * SCALE_; v0.y = a01 * SCALE_; v0.z = a02 * SCALE_; v0.w = a03 * SCALE_;
        v1.x = a10 * SCALE_; v1.y = a11 * SCALE_; v1.z = a12 * SCALE_; v1.w = a13 * SCALE_;
        *(float4*)(p_lds + (w * 2) * PSTR_ + 4 * hg)     = v0;
        *(float4*)(p_lds + (w * 2 + 1) * PSTR_ + 4 * hg) = v1;
      }
    }
    barrier_lgkm();   // p_lds ready; prefetch vmcnt NOT drained

    // --- online softmax: threads 0..255 = 16 h x 16 t ---
    if (tid < 256) {
      const int h2 = tid >> 4, tl2 = tid & 15;
      const float sv = p_lds[tl2 * PSTR_ + h2];
      float msub = sv;
#pragma unroll
      for (int d = 8; d; d >>= 1) msub = fmaxf(msub, __shfl_xor(msub, d, 16));
      const float mold = m_st[h2];
      const float mnew = fmaxf(mold, msub);
      const float e = __expf(sv - mnew);
      float lsum = e;
#pragma unroll
      for (int d = 8; d; d >>= 1) lsum += __shfl_xor(lsum, d, 16);
      p_lds[tl2 * PSTR_ + h2] = e;
      if (tl2 == 0) {
        const float fac = __expf(mold - mnew);
        f_st[h2] = fac;
        l_st[h2] = l_st[h2] * fac + lsum;
        m_st[h2] = mnew;
      }
    }
    barrier_lgkm();   // p/f/m/l ready; prefetch still in flight

    // --- PV accumulate: o[c-quad][h-quad] over 16 t ---
    {
      const float4 fv = *(const float4*)(f_st + 4 * h4p);
#pragma unroll
      for (int cc = 0; cc < 4; ++cc) {
        o[cc][0] *= fv.x; o[cc][1] *= fv.y; o[cc][2] *= fv.z; o[cc][3] *= fv.w;
      }
#pragma unroll 8
      for (int t = 0; t < TS_; ++t) {
        const float4 kq = *(const float4*)(bufc + t * CE_ + 4 * c4p);
        const float4 pq = *(const float4*)(p_lds + t * PSTR_ + 4 * h4p);
        o[0][0] = fmaf(pq.x, kq.x, o[0][0]); o[0][1] = fmaf(pq.y, kq.x, o[0][1]);
        o[0][2] = fmaf(pq.z, kq.x, o[0][2]); o[0][3] = fmaf(pq.w, kq.x, o[0][3]);
        o[1][0] = fmaf(pq.x, kq.y, o[1][0]); o[1][1] = fmaf(pq.y, kq.y, o[1][1]);
        o[1][2] = fmaf(pq.z, kq.y, o[1][2]); o[1][3] = fmaf(pq.w, kq.y, o[1][3]);
        o[2][0] = fmaf(pq.x, kq.z, o[2][0]); o[2][1] = fmaf(pq.y, kq.z, o[2][1]);
        o[2][2] = fmaf(pq.z, kq.z, o[2][2]); o[2][3] = fmaf(pq.w, kq.z, o[2][3]);
        o[3][0] = fmaf(pq.x, kq.w, o[3][0]); o[3][1] = fmaf(pq.y, kq.w, o[3][1]);
        o[3][2] = fmaf(pq.z, kq.w, o[3][2]); o[3][3] = fmaf(pq.w, kq.w, o[3][3]);
      }
    }
  }

  // --- write chunk partials ---
  {
    float* Op = ws + WS_OPART;
#pragma unroll
    for (int hh = 0; hh < 4; ++hh) {
      const int h = 4 * h4p + hh;
      float4 v;
      v.x = o[0][hh]; v.y = o[1][hh]; v.z = o[2][hh]; v.w = o[3][hh];
      *(float4*)(Op + ((size_t)(b * H_ + h) * NCH_ + chunk) * KVLR_ + 4 * c4p) = v;
    }
    if (tid < H_) {
      ws[WS_MLOC + (b * H_ + tid) * NCH_ + chunk] = m_st[tid];
      ws[WS_LLOC + (b * H_ + tid) * NCH_ + chunk] = l_st[tid];
    }
  }
}

// ---------------- K6: combine 64 partials + project through wkv_b[:,128:,:] ----------------
__global__ __launch_bounds__(256) void mla_k6(const float* __restrict__ wkvb,
                                              float* __restrict__ ws) {
  const int h = blockIdx.x, b = blockIdx.y;
  __shared__ float wgt[NCH_];
  __shared__ float ao[KVLR_];
  __shared__ float Linv;
  const int tid = threadIdx.x;
  if (tid < NCH_) {   // one wave: combine weights over 64 chunks
    const float m = ws[WS_MLOC + (b * H_ + h) * NCH_ + tid];
    float M = m;
#pragma unroll
    for (int s = 32; s; s >>= 1) M = fmaxf(M, __shfl_xor(M, s));
    const float wv = __expf(m - M);
    wgt[tid] = wv;
    float lv = ws[WS_LLOC + (b * H_ + h) * NCH_ + tid] * wv;
#pragma unroll
    for (int s = 32; s; s >>= 1) lv += __shfl_xor(lv, s);
    if (tid == 0) Linv = 1.0f / lv;
  }
  __syncthreads();
  const float* Ob = ws + WS_OPART + (size_t)(b * H_ + h) * NCH_ * KVLR_;
  float s0 = 0.f, s1 = 0.f;
#pragma unroll 4
  for (int i = 0; i < NCH_; ++i) {
    const float wv = wgt[i];
    s0 = fmaf(wv, Ob[(size_t)i * KVLR_ + tid], s0);
    s1 = fmaf(wv, Ob[(size_t)i * KVLR_ + tid + 256], s1);
  }
  const float li = Linv;
  ao[tid] = s0 * li;
  ao[tid + 256] = s1 * li;
  __syncthreads();

  const int w6 = tid >> 6, l6 = tid & 63;
  const float4 ax = *(const float4*)(ao + 4 * l6);
  const float4 bx = *(const float4*)(ao + 256 + 4 * l6);
  float* out2 = ws + WS_OUT2 + b * DIM_ + h * DV_;
#pragma unroll 2
  for (int k = 0; k < 32; k += 2) {
    const int v0 = w6 * 32 + k;
    const float4* w20 = (const float4*)(wkvb + ((size_t)h * 256 + DN_ + v0) * KVLR_);
    const float4* w21 = (const float4*)(wkvb + ((size_t)h * 256 + DN_ + v0 + 1) * KVLR_);
    const float4 a0 = w20[l6], c0 = w20[64 + l6];
    const float4 a1 = w21[l6], c1 = w21[64 + l6];
    float t0 = fmaf(a0.x, ax.x, fmaf(a0.y, ax.y, fmaf(a0.z, ax.z, fmaf(a0.w, ax.w,
               fmaf(c0.x, bx.x, fmaf(c0.y, bx.y, fmaf(c0.z, bx.z, c0.w * bx.w)))))));
    float t1 = fmaf(a1.x, ax.x, fmaf(a1.y, ax.y, fmaf(a1.z, ax.z, fmaf(a1.w, ax.w,
               fmaf(c1.x, bx.x, fmaf(c1.y, bx.y, fmaf(c1.z, bx.z, c1.w * bx.w)))))));
#pragma unroll
    for (int d = 32; d; d >>= 1) {
      t0 += __shfl_xor(t0, d);
      t1 += __shfl_xor(t1, d);
    }
    if (l6 == 0) { out2[v0] = t0; out2[v0 + 1] = t1; }
  }
}

// ---------------- K7: y = out2 @ wo^T + wo_b, 2 rows/wave ----------------
__global__ __launch_bounds__(256) void mla_k7(const float* __restrict__ wo,
                                              const float* __restrict__ wob,
                                              const float* __restrict__ ws,
                                              float* __restrict__ out) {
  const int w = threadIdx.x >> 6, l = threadIdx.x & 63;
  const int r0 = (blockIdx.x * 4 + w) * 2;  // 0..2046, grid 256
  const float4* w0p = (const float4*)(wo + (size_t)r0 * DIM_);
  const float4* w1p = (const float4*)(wo + (size_t)(r0 + 1) * DIM_);
  const float4* x4  = (const float4*)(ws + WS_OUT2);
  float4 wv0[8], wv1[8];
#pragma unroll
  for (int j = 0; j < 8; ++j) { wv0[j] = w0p[l + 64 * j]; wv1[j] = w1p[l + 64 * j]; }
  float acc0[B_], acc1[B_];
#pragma unroll
  for (int b = 0; b < B_; ++b) { acc0[b] = 0.f; acc1[b] = 0.f; }
#pragma unroll
  for (int b = 0; b < B_; ++b) {
#pragma unroll
    for (int j = 0; j < 8; ++j) {
      const float4 xv = x4[b * (DIM_ / 4) + l + 64 * j];
      acc0[b] = fmaf(wv0[j].x, xv.x, fmaf(wv0[j].y, xv.y, fmaf(wv0[j].z, xv.z, fmaf(wv0[j].w, xv.w, acc0[b]))));
      acc1[b] = fmaf(wv1[j].x, xv.x, fmaf(wv1[j].y, xv.y, fmaf(wv1[j].z, xv.z, fmaf(wv1[j].w, xv.w, acc1[b]))));
    }
  }
#pragma unroll
  for (int b = 0; b < B_; ++b)
#pragma unroll
    for (int s = 32; s; s >>= 1) {
      acc0[b] += __shfl_xor(acc0[b], s);
      acc1[b] += __shfl_xor(acc1[b], s);
    }
  if (l == 0) {
    const float b0 = wob[r0], b1 = wob[r0 + 1];
#pragma unroll
    for (int b = 0; b < B_; ++b) {
      out[b * DIM_ + r0]     = acc0[b] + b0;
      out[b * DIM_ + r0 + 1] = acc1[b] + b1;
    }
  }
}

extern "C" void kernel_launch(void* const* d_in, const int* in_sizes, int n_in,
                              void* d_out, int out_size, void* d_ws, size_t ws_size,
                              hipStream_t stream) {
  (void)in_sizes; (void)n_in; (void)out_size; (void)ws_size;
  const float* x     = (const float*)d_in[0];
  const float* fcos  = (const float*)d_in[2];
  const float* fsin  = (const float*)d_in[3];
  const float* kvpre = (const float*)d_in[4];
  const float* pepre = (const float*)d_in[5];
  const float* wqa   = (const float*)d_in[6];
  const float* bqa   = (const float*)d_in[7];
  const float* qnw   = (const float*)d_in[8];
  const float* wqb   = (const float*)d_in[9];
  const float* bqb   = (const float*)d_in[10];
  const float* wkva  = (const float*)d_in[11];
  const float* bkva  = (const float*)d_in[12];
  const float* kvnw  = (const float*)d_in[13];
  const float* wkvb  = (const float*)d_in[14];
  const float* wo    = (const float*)d_in[15];
  const float* wob   = (const float*)d_in[16];
  float* ws  = (float*)d_ws;
  float* out = (float*)d_out;

  mla_k1<<<dim3((QLR_ + CE_) / 8), dim3(256), 0, stream>>>(x, wqa, bqa, wkva, bkva, fcos, fsin, ws);
  mla_k3<<<dim3(H_ * (DN_ + DR_) / 8), dim3(256), 0, stream>>>(qnw, wqb, bqb, fcos, fsin, ws);
  mla_k4<<<dim3(16, H_), dim3(256), 0, stream>>>(wkvb, ws);
  mla_k5<<<dim3(NCH_, B_), dim3(512), 0, stream>>>(kvpre, pepre, kvnw, ws);
  mla_k6<<<dim3(H_, B_), dim3(256), 0, stream>>>(wkvb, ws);
  mla_k7<<<dim3(DIM_ / 8), dim3(256), 0, stream>>>(wo, wob, ws, out);
}

// Round 12
// 349.676 us; speedup vs baseline: 1.3983x; 1.0446x over previous
//
#include <hip/hip_runtime.h>
#include <math.h>

namespace {
constexpr int B_   = 8;
constexpr int DIM_ = 2048;
constexpr int H_   = 16;
constexpr int QLR_ = 1536;
constexpr int KVLR_= 512;
constexpr int DN_  = 128;
constexpr int DR_  = 64;
constexpr int DV_  = 128;
constexpr int TPRE_= 8191;
constexpr int CE_  = 576;    // KVLR + DR
constexpr int NCH_ = 32;     // chunks over T=8192
constexpr int CT_  = 256;    // t per chunk
constexpr int TS_  = 32;     // rows per LDS subtile (double-buffered)
constexpr int PSTR_= 20;     // p_lds row stride
constexpr float EPS_ = 1e-6f;
constexpr float SCALE_ = 0.07216878364870322f; // (DN+DR)^-0.5

// workspace layout (float offsets)
constexpr size_t WS_QLAT  = 0;
constexpr size_t WS_KVPE  = WS_QLAT  + (size_t)B_*QLR_;
constexpr size_t WS_KVNEW = WS_KVPE  + (size_t)B_*CE_;
constexpr size_t WS_PENEW = WS_KVNEW + (size_t)B_*KVLR_;
constexpr size_t WS_QRS   = WS_PENEW + (size_t)B_*DR_;
constexpr size_t WS_QNOPE = WS_QRS   + (size_t)B_;
constexpr size_t WS_QT    = WS_QNOPE + (size_t)B_*H_*DN_;   // qTT: [b][h][576]
constexpr size_t WS_MLOC  = WS_QT    + (size_t)B_*CE_*H_;
constexpr size_t WS_LLOC  = WS_MLOC  + (size_t)B_*H_*NCH_;
constexpr size_t WS_OUT2  = WS_LLOC  + (size_t)B_*H_*NCH_;
constexpr size_t WS_OPART = WS_OUT2  + (size_t)B_*DIM_;     // [b][h][chunk][512]
} // namespace

__device__ __forceinline__ void gload16(const float* src, float* ldsDst) {
  __builtin_amdgcn_global_load_lds((const __attribute__((address_space(1))) void*)src,
                                   (__attribute__((address_space(3))) void*)ldsDst,
                                   16, 0, 0);
}

// sum across each 16-lane group via DPP (VALU pipe, keeps DS unit free)
__device__ __forceinline__ float rsum16(float v) {
  int x = __float_as_int(v);
  v += __int_as_float(__builtin_amdgcn_update_dpp(0, x, 0xB1, 0xF, 0xF, true));  // quad_perm xor1
  x = __float_as_int(v);
  v += __int_as_float(__builtin_amdgcn_update_dpp(0, x, 0x4E, 0xF, 0xF, true));  // quad_perm xor2
  x = __float_as_int(v);
  v += __int_as_float(__builtin_amdgcn_update_dpp(0, x, 0x141, 0xF, 0xF, true)); // row_half_mirror
  x = __float_as_int(v);
  v += __int_as_float(__builtin_amdgcn_update_dpp(0, x, 0x140, 0xF, 0xF, true)); // row_mirror
  return v;
}

// ---------------- K1: q_latent = x@wq_a^T + b ; kvpe = x@wkv_a^T + b ----------------
__global__ __launch_bounds__(256) void mla_k1(const float* __restrict__ x,
                                              const float* __restrict__ wqa,
                                              const float* __restrict__ bqa,
                                              const float* __restrict__ wkva,
                                              const float* __restrict__ bkva,
                                              float* __restrict__ ws) {
  const int w = threadIdx.x >> 6, l = threadIdx.x & 63;
  const int r = blockIdx.x * 4 + w;  // 0..2111
  const float* W; const float* bias; float* out; int rr; int ostride;
  if (r < QLR_) { W = wqa;  bias = bqa;  out = ws + WS_QLAT; rr = r;        ostride = QLR_; }
  else          { W = wkva; bias = bkva; out = ws + WS_KVPE; rr = r - QLR_; ostride = CE_;  }
  const float4* wp = (const float4*)(W + (size_t)rr * DIM_);
  const float4* x4 = (const float4*)x;
  float4 wv[8];
#pragma unroll
  for (int j = 0; j < 8; ++j) wv[j] = wp[l + 64 * j];
  float acc[B_];
#pragma unroll
  for (int b = 0; b < B_; ++b) acc[b] = 0.f;
#pragma unroll
  for (int b = 0; b < B_; ++b) {
#pragma unroll
    for (int j = 0; j < 8; ++j) {
      const float4 xv = x4[b * (DIM_ / 4) + l + 64 * j];
      acc[b] = fmaf(wv[j].x, xv.x, fmaf(wv[j].y, xv.y, fmaf(wv[j].z, xv.z, fmaf(wv[j].w, xv.w, acc[b]))));
    }
  }
#pragma unroll
  for (int b = 0; b < B_; ++b)
#pragma unroll
    for (int s = 32; s; s >>= 1) acc[b] += __shfl_xor(acc[b], s);
  if (l == 0) {
    const float b0 = bias[rr];
#pragma unroll
    for (int b = 0; b < B_; ++b) out[b * ostride + rr] = acc[b] + b0;
  }
}

// ---------------- K2: kv rms-norm + k_pe rope + q rms scales ----------------
__global__ __launch_bounds__(256) void mla_k2(const float* __restrict__ kvnw,
                                              const float* __restrict__ fcos,
                                              const float* __restrict__ fsin,
                                              float* __restrict__ ws) {
  const int tid = threadIdx.x;
  const int b = tid >> 5, i = tid & 31;
  const float* kvpe = ws + WS_KVPE + b * CE_;
  float ss = 0.f;
#pragma unroll
  for (int j = 0; j < KVLR_ / 32; ++j) { const float v = kvpe[i + 32 * j]; ss = fmaf(v, v, ss); }
#pragma unroll
  for (int s = 16; s; s >>= 1) ss += __shfl_xor(ss, s, 32);
  const float scale = 1.0f / sqrtf(ss / (float)KVLR_ + EPS_);
  float* kvn = ws + WS_KVNEW + b * KVLR_;
#pragma unroll
  for (int j = 0; j < KVLR_ / 32; ++j) {
    const int c = i + 32 * j;
    kvn[c] = kvpe[c] * kvnw[c] * scale;
  }
  { // rope new k_pe
    const float xr = kvpe[KVLR_ + 2 * i], xi = kvpe[KVLR_ + 2 * i + 1];
    const float c = fcos[i], s = fsin[i];
    float* pen = ws + WS_PENEW + b * DR_;
    pen[2 * i]     = xr * c - xi * s;
    pen[2 * i + 1] = xr * s + xi * c;
  }
  { // q latent rms scale per batch
    const float* p = ws + WS_QLAT + b * QLR_;
    float sq = 0.f;
#pragma unroll
    for (int j = 0; j < QLR_ / 32; ++j) { const float v = p[i + 32 * j]; sq = fmaf(v, v, sq); }
#pragma unroll
    for (int s = 16; s; s >>= 1) sq += __shfl_xor(sq, s, 32);
    if (i == 0) ws[WS_QRS + b] = 1.0f / sqrtf(sq / (float)QLR_ + EPS_);
  }
}

// ---------------- K3: q = rms(q_lat)*g @ wq_b^T + b ; split nope / rope(pe) ----------------
__global__ __launch_bounds__(256) void mla_k3(const float* __restrict__ qnw,
                                              const float* __restrict__ wqb,
                                              const float* __restrict__ bqb,
                                              const float* __restrict__ fcos,
                                              const float* __restrict__ fsin,
                                              float* __restrict__ ws) {
  const int w = threadIdx.x >> 6, l = threadIdx.x & 63;
  const int r0 = blockIdx.x * 8 + w * 2;  // 0..3070
  const float4* w0p = (const float4*)(wqb + (size_t)r0 * QLR_);
  const float4* w1p = (const float4*)(wqb + (size_t)(r0 + 1) * QLR_);
  const float4* g4  = (const float4*)qnw;
  const float4* x4  = (const float4*)(ws + WS_QLAT);
  float4 wg0[6], wg1[6];
#pragma unroll
  for (int j = 0; j < 6; ++j) {
    const int c4 = l + 64 * j;
    const float4 a = w0p[c4], bb = w1p[c4], g = g4[c4];
    wg0[j].x = a.x * g.x; wg0[j].y = a.y * g.y; wg0[j].z = a.z * g.z; wg0[j].w = a.w * g.w;
    wg1[j].x = bb.x * g.x; wg1[j].y = bb.y * g.y; wg1[j].z = bb.z * g.z; wg1[j].w = bb.w * g.w;
  }
  float acc0[B_], acc1[B_];
#pragma unroll
  for (int b = 0; b < B_; ++b) { acc0[b] = 0.f; acc1[b] = 0.f; }
#pragma unroll
  for (int b = 0; b < B_; ++b) {
#pragma unroll
    for (int j = 0; j < 6; ++j) {
      const float4 xv = x4[b * (QLR_ / 4) + l + 64 * j];
      acc0[b] = fmaf(wg0[j].x, xv.x, fmaf(wg0[j].y, xv.y, fmaf(wg0[j].z, xv.z, fmaf(wg0[j].w, xv.w, acc0[b]))));
      acc1[b] = fmaf(wg1[j].x, xv.x, fmaf(wg1[j].y, xv.y, fmaf(wg1[j].z, xv.z, fmaf(wg1[j].w, xv.w, acc1[b]))));
    }
  }
#pragma unroll
  for (int b = 0; b < B_; ++b)
#pragma unroll
    for (int s = 32; s; s >>= 1) {
      acc0[b] += __shfl_xor(acc0[b], s);
      acc1[b] += __shfl_xor(acc1[b], s);
    }
  if (l == 0) {
    const int h = r0 / (DN_ + DR_);
    const int j0 = r0 - h * (DN_ + DR_);
    const float b0 = bqb[r0], b1 = bqb[r0 + 1];
    if (j0 < DN_) {
      float* qn = ws + WS_QNOPE;
#pragma unroll
      for (int b = 0; b < B_; ++b) {
        const float sb = ws[WS_QRS + b];
        qn[(b * H_ + h) * DN_ + j0]     = acc0[b] * sb + b0;
        qn[(b * H_ + h) * DN_ + j0 + 1] = acc1[b] * sb + b1;
      }
    } else {
      const int i = (j0 - DN_) >> 1;
      const float c = fcos[i], s = fsin[i];
      float* qTT = ws + WS_QT;
#pragma unroll
      for (int b = 0; b < B_; ++b) {
        const float sb = ws[WS_QRS + b];
        const float xr = acc0[b] * sb + b0, xi = acc1[b] * sb + b1;
        qTT[((size_t)(b * H_ + h)) * CE_ + KVLR_ + 2 * i]     = xr * c - xi * s;
        qTT[((size_t)(b * H_ + h)) * CE_ + KVLR_ + 2 * i + 1] = xr * s + xi * c;
      }
    }
  }
}

// ---------------- K4: q_abs[b][h][c] = sum_d q_nope[b][h][d] * wkv_b[h][d][c] ----------------
__global__ __launch_bounds__(256) void mla_k4(const float* __restrict__ wkvb,
                                              float* __restrict__ ws) {
  __shared__ float red[7 * 32 * B_];
  const int h = blockIdx.y;
  const int strip = blockIdx.x;
  const int tid = threadIdx.x;
  const int c = tid & 31, dg = tid >> 5;
  const int cg = strip * 32 + c;
  const float* qn = ws + WS_QNOPE;
  float acc[B_];
#pragma unroll
  for (int b = 0; b < B_; ++b) acc[b] = 0.f;
  const float* wp = wkvb + (size_t)h * 256 * KVLR_ + cg;
#pragma unroll
  for (int dd = 0; dd < 16; ++dd) {
    const int d = dg * 16 + dd;
    const float wv = wp[(size_t)d * KVLR_];
#pragma unroll
    for (int b = 0; b < B_; ++b) acc[b] = fmaf(qn[(b * H_ + h) * DN_ + d], wv, acc[b]);
  }
  if (dg > 0) {
#pragma unroll
    for (int b = 0; b < B_; ++b) red[(((dg - 1) * 32) + c) * B_ + b] = acc[b];
  }
  __syncthreads();
  if (dg == 0) {
    float* qTT = ws + WS_QT;
#pragma unroll
    for (int b = 0; b < B_; ++b) {
      float v = acc[b];
#pragma unroll
      for (int g = 0; g < 7; ++g) v += red[(g * 32 + c) * B_ + b];
      qTT[((size_t)(b * H_ + h)) * CE_ + cg] = v;
    }
  }
}

// ---------------- K5: fused flash-decode, q-in-registers, spill-free ----------------
// 512 thr, grid (32, 8), 1 block/CU (147 KB LDS). TS=32 double-buffered kv via
// global_load_lds. Score: thread = (t8-group, h-pair, c-split16); q[2][36]
// persistent in VGPRs; tt-outer loop keeps live state ~110 VGPRs (no spill).
// DPP reduce over 16 c-split lanes. PV: thread = (c-quad, h-quad), o[4][4]
// persistent. All 8 waves active in every phase. Session-best measured config.
__global__ __launch_bounds__(512) void mla_k5(const float* __restrict__ kvpre,
                                              const float* __restrict__ pepre,
                                              float* __restrict__ ws) {
  __shared__ float kv_lds[2][TS_ * CE_];  // 2 x 32 x 576 x 4B = 147.5 KB
  __shared__ float p_lds[TS_ * PSTR_];    // 2.5 KB
  __shared__ float m_st[H_], l_st[H_], f_st[H_];

  const int b = blockIdx.y, chunk = blockIdx.x;
  const int t0 = chunk * CT_;
  const int tid = threadIdx.x;
  const int w = tid >> 6, l = tid & 63;
  // score roles
  const int cs = l & 15;             // c-split: 36 floats each
  const int hl = l >> 4;             // 0..3
  const int tg = w >> 1;             // t-group: rows tg*8 .. tg*8+7
  const int hg = (w & 1) * 4 + hl;   // 0..7 -> heads 2hg, 2hg+1
  // PV roles
  const int c4p = tid >> 2, h4p = tid & 3;

  const float* kvnew = ws + WS_KVNEW + b * KVLR_;
  const float* penew = ws + WS_PENEW + b * DR_;

  auto stageKV = [&](float* buf, int s) {
    const int ts0 = t0 + s * TS_;
#pragma unroll
    for (int k = 0; k < 9; ++k) {          // 32*576/4 = 4608 f4 / 512 thr = 9
      const int i = w + 8 * k;             // wave-strided instr index
      const int f = i * 64 + l;            // f4 index in subtile
      const int tl = f / 144;
      const int c4 = f - tl * 144;
      const int tgl = ts0 + tl;
      const float* src;
      if (tgl < TPRE_) {
        src = (c4 < 128) ? (kvpre + ((size_t)b * TPRE_ + tgl) * KVLR_ + 4 * c4)
                         : (pepre + ((size_t)b * TPRE_ + tgl) * DR_ + 4 * (c4 - 128));
      } else {
        src = (c4 < 128) ? (kvnew + 4 * c4) : (penew + 4 * (c4 - 128));
      }
      gload16(src, buf + (size_t)i * 64 * 4);
    }
  };

  stageKV(kv_lds[0], 0);   // start HBM early

  // --- persistent q registers: heads 2hg, 2hg+1, c-range [cs*36, cs*36+36) ---
  float4 q0v[9], q1v[9];
  {
    const float* qb0 = ws + WS_QT + ((size_t)(b * H_) + 2 * hg) * CE_ + cs * 36;
    const float* qb1 = qb0 + CE_;
#pragma unroll
    for (int j = 0; j < 9; ++j) {
      q0v[j] = *(const float4*)(qb0 + 4 * j);
      q1v[j] = *(const float4*)(qb1 + 4 * j);
    }
  }
  if (tid < H_) { m_st[tid] = -3.4e38f; l_st[tid] = 0.f; }

  float o[4][4];
#pragma unroll
  for (int cc = 0; cc < 4; ++cc)
#pragma unroll
    for (int hh = 0; hh < 4; ++hh) o[cc][hh] = 0.f;

  for (int s = 0; s < CT_ / TS_; ++s) {   // 8 subtiles of 32 rows
    __syncthreads();                       // buf[s&1] staged; prev PV reads done
    if (s + 1 < CT_ / TS_) stageKV(kv_lds[(s + 1) & 1], s + 1);  // prefetch
    const float* bufc = kv_lds[s & 1];

    // --- scores: 8 t-rows x 2 h x 36 c per thread; tt-outer keeps regs low ---
    {
      const float* kb = bufc + (tg * 8) * CE_ + cs * 36;
#pragma unroll
      for (int tt = 0; tt < 8; ++tt) {
        const float* kr = kb + tt * CE_;
        float a0 = 0.f, a1 = 0.f;
#pragma unroll
        for (int j = 0; j < 9; ++j) {
          const float4 k = *(const float4*)(kr + 4 * j);
          const float4 qa = q0v[j], qc = q1v[j];
          a0 = fmaf(k.x, qa.x, fmaf(k.y, qa.y, fmaf(k.z, qa.z, fmaf(k.w, qa.w, a0))));
          a1 = fmaf(k.x, qc.x, fmaf(k.y, qc.y, fmaf(k.z, qc.z, fmaf(k.w, qc.w, a1))));
        }
        a0 = rsum16(a0);
        a1 = rsum16(a1);
        if (cs == 0) {
          float2 v; v.x = a0 * SCALE_; v.y = a1 * SCALE_;
          *(float2*)(p_lds + (tg * 8 + tt) * PSTR_ + 2 * hg) = v;
        }
      }
    }
    __syncthreads();

    // --- online softmax: 16 h x 32 t (all 512 threads) ---
    {
      const int h2 = tid >> 5, tl2 = tid & 31;
      const float sv = p_lds[tl2 * PSTR_ + h2];
      float msub = sv;
#pragma unroll
      for (int d = 16; d; d >>= 1) msub = fmaxf(msub, __shfl_xor(msub, d, 32));
      const float mold = m_st[h2];
      const float mnew = fmaxf(mold, msub);
      const float e = __expf(sv - mnew);
      float lsum = e;
#pragma unroll
      for (int d = 16; d; d >>= 1) lsum += __shfl_xor(lsum, d, 32);
      p_lds[tl2 * PSTR_ + h2] = e;
      if (tl2 == 0) {
        const float fac = __expf(mold - mnew);
        f_st[h2] = fac;
        l_st[h2] = l_st[h2] * fac + lsum;
        m_st[h2] = mnew;
      }
    }
    __syncthreads();

    // --- PV accumulate: o[c-quad][h-quad] over 32 t ---
    {
      const float4 fv = *(const float4*)(f_st + 4 * h4p);
#pragma unroll
      for (int cc = 0; cc < 4; ++cc) {
        o[cc][0] *= fv.x; o[cc][1] *= fv.y; o[cc][2] *= fv.z; o[cc][3] *= fv.w;
      }
#pragma unroll 8
      for (int t = 0; t < TS_; ++t) {
        const float4 kq = *(const float4*)(bufc + t * CE_ + 4 * c4p);
        const float4 pq = *(const float4*)(p_lds + t * PSTR_ + 4 * h4p);
        o[0][0] = fmaf(pq.x, kq.x, o[0][0]); o[0][1] = fmaf(pq.y, kq.x, o[0][1]);
        o[0][2] = fmaf(pq.z, kq.x, o[0][2]); o[0][3] = fmaf(pq.w, kq.x, o[0][3]);
        o[1][0] = fmaf(pq.x, kq.y, o[1][0]); o[1][1] = fmaf(pq.y, kq.y, o[1][1]);
        o[1][2] = fmaf(pq.z, kq.y, o[1][2]); o[1][3] = fmaf(pq.w, kq.y, o[1][3]);
        o[2][0] = fmaf(pq.x, kq.z, o[2][0]); o[2][1] = fmaf(pq.y, kq.z, o[2][1]);
        o[2][2] = fmaf(pq.z, kq.z, o[2][2]); o[2][3] = fmaf(pq.w, kq.z, o[2][3]);
        o[3][0] = fmaf(pq.x, kq.w, o[3][0]); o[3][1] = fmaf(pq.y, kq.w, o[3][1]);
        o[3][2] = fmaf(pq.z, kq.w, o[3][2]); o[3][3] = fmaf(pq.w, kq.w, o[3][3]);
      }
    }
  }

  // --- write chunk partials ---
  {
    float* Op = ws + WS_OPART;
#pragma unroll
    for (int hh = 0; hh < 4; ++hh) {
      const int h = 4 * h4p + hh;
      float4 v;
      v.x = o[0][hh]; v.y = o[1][hh]; v.z = o[2][hh]; v.w = o[3][hh];
      *(float4*)(Op + ((size_t)(b * H_ + h) * NCH_ + chunk) * KVLR_ + 4 * c4p) = v;
    }
    if (tid < H_) {
      ws[WS_MLOC + (b * H_ + tid) * NCH_ + chunk] = m_st[tid];
      ws[WS_LLOC + (b * H_ + tid) * NCH_ + chunk] = l_st[tid];
    }
  }
}

// ---------------- K6: combine partials + project through wkv_b[:,128:,:] ----------------
__global__ __launch_bounds__(256) void mla_k6(const float* __restrict__ wkvb,
                                              float* __restrict__ ws) {
  const int h = blockIdx.x, b = blockIdx.y;
  __shared__ float wgt[NCH_];
  __shared__ float ao[KVLR_];
  __shared__ float Linv;
  const int tid = threadIdx.x;
  if (tid < NCH_) {   // 32 lanes: combine weights
    const float m = ws[WS_MLOC + (b * H_ + h) * NCH_ + tid];
    float M = m;
#pragma unroll
    for (int s = 16; s; s >>= 1) M = fmaxf(M, __shfl_xor(M, s, 32));
    const float wv = __expf(m - M);
    wgt[tid] = wv;
    float lv = ws[WS_LLOC + (b * H_ + h) * NCH_ + tid] * wv;
#pragma unroll
    for (int s = 16; s; s >>= 1) lv += __shfl_xor(lv, s, 32);
    if (tid == 0) Linv = 1.0f / lv;
  }
  __syncthreads();
  const float* Ob = ws + WS_OPART + (size_t)(b * H_ + h) * NCH_ * KVLR_;
  float s0 = 0.f, s1 = 0.f;
#pragma unroll 4
  for (int i = 0; i < NCH_; ++i) {
    const float wv = wgt[i];
    s0 = fmaf(wv, Ob[(size_t)i * KVLR_ + tid], s0);
    s1 = fmaf(wv, Ob[(size_t)i * KVLR_ + tid + 256], s1);
  }
  const float li = Linv;
  ao[tid] = s0 * li;
  ao[tid + 256] = s1 * li;
  __syncthreads();
  const int v = tid >> 1, half = tid & 1;
  const float* w2 = wkvb + ((size_t)h * 256 + DN_ + v) * KVLR_ + half * 256;
  const float* a = ao + half * 256;
  float s = 0.f;
#pragma unroll
  for (int c = 0; c < 256; c += 4) {
    const float4 wv = *(const float4*)(w2 + c);
    s = fmaf(wv.x, a[c], s);
    s = fmaf(wv.y, a[c + 1], s);
    s = fmaf(wv.z, a[c + 2], s);
    s = fmaf(wv.w, a[c + 3], s);
  }
  s += __shfl_xor(s, 1);
  if (half == 0) ws[WS_OUT2 + b * DIM_ + h * DV_ + v] = s;
}

// ---------------- K7: y = out2 @ wo^T + wo_b ----------------
__global__ __launch_bounds__(256) void mla_k7(const float* __restrict__ wo,
                                              const float* __restrict__ wob,
                                              const float* __restrict__ ws,
                                              float* __restrict__ out) {
  const int w = threadIdx.x >> 6, l = threadIdx.x & 63;
  const int r = blockIdx.x * 4 + w;  // 0..2047
  const float4* wp = (const float4*)(wo + (size_t)r * DIM_);
  const float4* x4 = (const float4*)(ws + WS_OUT2);
  float4 wv[8];
#pragma unroll
  for (int j = 0; j < 8; ++j) wv[j] = wp[l + 64 * j];
  float acc[B_];
#pragma unroll
  for (int b = 0; b < B_; ++b) acc[b] = 0.f;
#pragma unroll
  for (int b = 0; b < B_; ++b) {
#pragma unroll
    for (int j = 0; j < 8; ++j) {
      const float4 xv = x4[b * (DIM_ / 4) + l + 64 * j];
      acc[b] = fmaf(wv[j].x, xv.x, fmaf(wv[j].y, xv.y, fmaf(wv[j].z, xv.z, fmaf(wv[j].w, xv.w, acc[b]))));
    }
  }
#pragma unroll
  for (int b = 0; b < B_; ++b)
#pragma unroll
    for (int s = 32; s; s >>= 1) acc[b] += __shfl_xor(acc[b], s);
  if (l == 0) {
    const float b0 = wob[r];
#pragma unroll
    for (int b = 0; b < B_; ++b) out[b * DIM_ + r] = acc[b] + b0;
  }
}

extern "C" void kernel_launch(void* const* d_in, const int* in_sizes, int n_in,
                              void* d_out, int out_size, void* d_ws, size_t ws_size,
                              hipStream_t stream) {
  (void)in_sizes; (void)n_in; (void)out_size; (void)ws_size;
  const float* x     = (const float*)d_in[0];
  const float* fcos  = (const float*)d_in[2];
  const float* fsin  = (const float*)d_in[3];
  const float* kvpre = (const float*)d_in[4];
  const float* pepre = (const float*)d_in[5];
  const float* wqa   = (const float*)d_in[6];
  const float* bqa   = (const float*)d_in[7];
  const float* qnw   = (const float*)d_in[8];
  const float* wqb   = (const float*)d_in[9];
  const float* bqb   = (const float*)d_in[10];
  const float* wkva  = (const float*)d_in[11];
  const float* bkva  = (const float*)d_in[12];
  const float* kvnw  = (const float*)d_in[13];
  const float* wkvb  = (const float*)d_in[14];
  const float* wo    = (const float*)d_in[15];
  const float* wob   = (const float*)d_in[16];
  float* ws  = (float*)d_ws;
  float* out = (float*)d_out;

  mla_k1<<<dim3((QLR_ + CE_) / 4), dim3(256), 0, stream>>>(x, wqa, bqa, wkva, bkva, ws);
  mla_k2<<<dim3(1), dim3(256), 0, stream>>>(kvnw, fcos, fsin, ws);
  mla_k3<<<dim3(H_ * (DN_ + DR_) / 8), dim3(256), 0, stream>>>(qnw, wqb, bqb, fcos, fsin, ws);
  mla_k4<<<dim3(16, H_), dim3(256), 0, stream>>>(wkvb, ws);
  mla_k5<<<dim3(NCH_, B_), dim3(512), 0, stream>>>(kvpre, pepre, ws);
  mla_k6<<<dim3(H_, B_), dim3(256), 0, stream>>>(wkvb, ws);
  mla_k7<<<dim3(DIM_ / 4), dim3(256), 0, stream>>>(wo, wob, ws, out);
}